// Round 8
// baseline (315.045 us; speedup 1.0000x reference)
//
#include <hip/hip_runtime.h>
#include <stdint.h>

// ---------- types ----------
typedef _Float16 half8 __attribute__((ext_vector_type(8)));   // 8 fp16 (4 VGPRs) MFMA frag
typedef __attribute__((ext_vector_type(4))) float f32x4;      // MFMA acc
typedef __attribute__((ext_vector_type(4))) unsigned short us4;

__device__ __forceinline__ unsigned short f2h(float f) {
  _Float16 h = (_Float16)f;              // v_cvt_f16_f32, RTE
  return __builtin_bit_cast(unsigned short, h);
}

// async global->LDS, 16B per lane (dst = wave-uniform base + lane*16)
__device__ __forceinline__ void async_cp16(const unsigned short* g, unsigned short* l) {
  __builtin_amdgcn_global_load_lds(
      (const __attribute__((address_space(1))) void*)g,
      (__attribute__((address_space(3))) void*)l, 16, 0, 0);
}

// =====================================================================
// Round-8 GEMM core: R2 schedule + CROSS-PHASE READ PIPELINING + T5.
// 256x256 tile, C = A[M,1024] * B[N,1024]^T, fp16 in / fp32 acc,
// 512 threads = 8 waves (2M x 4N), per-wave 128x64, 16x16x32 MFMA.
//
// vs R2 (72 us, 41% MfmaUtil): ds_reads for phase p+1's MFMA issue in
// phase p; MFMA consumes regs read one phase earlier, so each wave's
// read latency hides under its own MFMA burst (the m201 read placement,
// untested in isolation — R3 confounded it with vmcnt(0) drains).
// Boundary: next-tile kh0 reads CANNOT prefetch at P4 (cross-wave race:
// vmcnt is per-wave, chunks staged by other waves), so P1 reads its own
// MFMA inputs too (12 reads; only first 8 gate P1's MFMA via the
// compiler's partial lgkm wait).
//   P1: read bP<-Bkh0, aP<-Akh0mh0, aQ<-Akh0mh1 | ST1-A | MFMA(aP,bP)->acc0..3
//   P2: read bQ<-Bkh1, aP<-Akh1mh0             | ST1-B | MFMA(aQ,bP)->acc4..7
//   P3: read aQ<-Akh1mh1                       | ST2-A | MFMA(aP,bQ)->acc0..3
//   P4: (no reads)                             | ST2-B | MFMA(aQ,bQ)->acc4..7 | vmcnt
// Staging positions, barrier count, and counted-vmcnt(4) ledger are
// IDENTICAL to the verified R2. WAR walk: each LDS region has >=2
// barriers between last read consumption and DMA overwrite (unchanged).
// T5 setprio(1) around MFMA clusters (catalog: gated on this structure).
//
// LDS: [buf(2)][A/B][kh(2)][256 rows x 32 cols] = 128 KiB.
// Swizzle: 16B chunk kq of row r at slot (kq+(r>>1))&3; inverse applied
// to the global source address (linear LDS dst). 0 bank conflicts.
// =====================================================================

#define BARF() { asm volatile("" ::: "memory"); \
                 __builtin_amdgcn_s_barrier(); \
                 asm volatile("" ::: "memory"); }

#define MFMA_PH(AS, BS, IOFF) \
  __builtin_amdgcn_s_setprio(1); \
  _Pragma("unroll") \
  for (int ii = 0; ii < 4; ++ii) { \
    _Pragma("unroll") \
    for (int jj = 0; jj < 4; ++jj) \
      acc[(IOFF) + ii][jj] = __builtin_amdgcn_mfma_f32_16x16x32_f16( \
          AS[ii], BS[jj], acc[(IOFF) + ii][jj], 0, 0, 0); \
  } \
  __builtin_amdgcn_s_setprio(0);

// One K-tile (4 single-barrier phases). BUF = J&1 (literal). J = runtime.
// WAITN: 4 = steady-state counted wait, 0 = tail drain, -1 = none.
#define KTILE(BUF, J, ST1, ST2, WAITN) { \
  /* ---- P1: reads (bP,aP gate; aQ for P2) + stage (J+1) A-kh1 + MFMA(aP,bP) ---- */ \
  BARF(); \
  { \
    _Pragma("unroll") \
    for (int jj = 0; jj < 4; ++jj) bP[jj] = *(const half8*)&lds[(BUF)*32768 + 16384 + offB[jj]]; \
    _Pragma("unroll") \
    for (int ii = 0; ii < 4; ++ii) aP[ii] = *(const half8*)&lds[(BUF)*32768 + offA[ii]]; \
    _Pragma("unroll") \
    for (int ii = 0; ii < 4; ++ii) aQ[ii] = *(const half8*)&lds[(BUF)*32768 + offA[4 + ii]]; \
    if (ST1) { const unsigned short* s_ = sA + (J + 1) * 64 + 32; \
      async_cp16(s_ + g0, lds + (1 - (BUF)) * 32768 + 8192 + d0); \
      async_cp16(s_ + g1, lds + (1 - (BUF)) * 32768 + 8192 + d1); } \
    MFMA_PH(aP, bP, 0) \
  } \
  /* ---- P2: reads for P3 (bQ, aP<-kh1mh0) + stage (J+1) B-kh1 + MFMA(aQ,bP) ---- */ \
  BARF(); \
  { \
    _Pragma("unroll") \
    for (int jj = 0; jj < 4; ++jj) bQ[jj] = *(const half8*)&lds[(BUF)*32768 + 24576 + offB[jj]]; \
    _Pragma("unroll") \
    for (int ii = 0; ii < 4; ++ii) aP[ii] = *(const half8*)&lds[(BUF)*32768 + 8192 + offA[ii]]; \
    if (ST1) { const unsigned short* s_ = sB + (J + 1) * 64 + 32; \
      async_cp16(s_ + g0, lds + (1 - (BUF)) * 32768 + 24576 + d0); \
      async_cp16(s_ + g1, lds + (1 - (BUF)) * 32768 + 24576 + d1); } \
    MFMA_PH(aQ, bP, 4) \
  } \
  /* ---- P3: read for P4 (aQ<-kh1mh1) + stage (J+2) A-kh0 + MFMA(aP,bQ) ---- */ \
  BARF(); \
  { \
    _Pragma("unroll") \
    for (int ii = 0; ii < 4; ++ii) aQ[ii] = *(const half8*)&lds[(BUF)*32768 + 8192 + offA[4 + ii]]; \
    if (ST2) { const unsigned short* s_ = sA + (J + 2) * 64; \
      async_cp16(s_ + g0, lds + (BUF) * 32768 + d0); \
      async_cp16(s_ + g1, lds + (BUF) * 32768 + d1); } \
    MFMA_PH(aP, bQ, 0) \
  } \
  /* ---- P4: no reads; stage (J+2) B-kh0 + MFMA(aQ,bQ); boundary vmcnt ---- */ \
  BARF(); \
  { \
    if (ST2) { const unsigned short* s_ = sB + (J + 2) * 64; \
      async_cp16(s_ + g0, lds + (BUF) * 32768 + 16384 + d0); \
      async_cp16(s_ + g1, lds + (BUF) * 32768 + 16384 + d1); } \
    MFMA_PH(aQ, bQ, 4) \
  } \
  if ((WAITN) == 4)      asm volatile("s_waitcnt vmcnt(4)" ::: "memory"); \
  else if ((WAITN) == 0) asm volatile("s_waitcnt vmcnt(0)" ::: "memory"); \
}

template<int EPI>   // 0 = fp32 C, 1 = fp16 C
__device__ __forceinline__ void gemm256_core(
    const unsigned short* __restrict__ pA, const unsigned short* __restrict__ pB,
    void* __restrict__ C0, int m0, int n0, unsigned short* lds)
{
  const int t = threadIdx.x;

  // ---- staging per-thread constants (pid -> (row, slot) -> logical kq) ----
  const int r0 = t >> 2;
  const int kq0 = ((t & 3) - (r0 >> 1)) & 3;
  const int r1 = (512 + t) >> 2;
  const int kq1 = ((t & 3) - (r1 >> 1)) & 3;
  const long g0 = (long)r0 * 1024 + kq0 * 8;   // global elem offset (row-major, K=1024)
  const long g1 = (long)r1 * 1024 + kq1 * 8;
  const int d0 = t * 8;                        // LDS elem offset of chunk pid0 (=t)
  const int d1 = (512 + t) * 8;                // chunk pid1 (=512+t)

  const unsigned short* sA = pA + (long)m0 * 1024;
  const unsigned short* sB = pB + (long)n0 * 1024;

  // ---- MFMA fragment geometry ----
  const int w  = t >> 6;
  const int l  = t & 63;
  const int wm = (w >> 2) * 128;     // 2 m-waves
  const int wn = (w & 3) * 64;       // 4 n-waves
  const int lm = l & 15;
  const int kq = l >> 4;

  // loop-invariant swizzled LDS read offsets (elements, region-relative)
  int offA[8], offB[4];
  #pragma unroll
  for (int i = 0; i < 8; ++i) {
    int r = wm + i * 16 + lm;
    offA[i] = r * 32 + (((kq + (r >> 1)) & 3) * 8);
  }
  #pragma unroll
  for (int j = 0; j < 4; ++j) {
    int r = wn + j * 16 + lm;
    offB[j] = r * 32 + (((kq + (r >> 1)) & 3) * 8);
  }

  f32x4 acc[8][4];
  #pragma unroll
  for (int i = 0; i < 8; ++i)
    #pragma unroll
    for (int j = 0; j < 4; ++j)
      acc[i][j] = (f32x4){0.f, 0.f, 0.f, 0.f};

  half8 aP[4], aQ[4], bP[4], bQ[4];

  // ---- prologue: stage buf0 {A,B}x{kh0,kh1} + buf1 {A,B} kh0 (12 loads) ----
  async_cp16(sA + g0,      lds + 0     + d0);  async_cp16(sA + g1,      lds + 0     + d1);
  async_cp16(sB + g0,      lds + 16384 + d0);  async_cp16(sB + g1,      lds + 16384 + d1);
  async_cp16(sA + g0 + 32, lds + 8192  + d0);  async_cp16(sA + g1 + 32, lds + 8192  + d1);
  async_cp16(sB + g0 + 32, lds + 24576 + d0);  async_cp16(sB + g1 + 32, lds + 24576 + d1);
  async_cp16(sA + g0 + 64, lds + 32768 + d0);  async_cp16(sA + g1 + 64, lds + 32768 + d1);
  async_cp16(sB + g0 + 64, lds + 49152 + d0);  async_cp16(sB + g1 + 64, lds + 49152 + d1);
  asm volatile("s_waitcnt vmcnt(4)" ::: "memory");   // buf0 fully landed; buf1-kh0 in flight
  // (first KTILE's P1 barrier completes the cross-wave handoff)

  // ---- main loop: K = 1024 -> 16 K-tiles ----
  for (int j2 = 0; j2 < 7; ++j2) {
    const int j = j2 * 2;
    KTILE(0, j,     1, 1, 4)
    KTILE(1, j + 1, 1, 1, 4)
  }
  KTILE(0, 14, 1, 0, 0)    // stages tile 15 kh1; drains everything
  KTILE(1, 15, 0, 0, -1)   // pure compute tail

  // ---- epilogue. C/D layout (m89-verified): col = lane&15, row = (lane>>4)*4 + reg ----
  const int cr = wm + (l >> 4) * 4;
  const int cc = wn + lm;
  if (EPI == 0) {
    float* C = (float*)C0;
    #pragma unroll
    for (int i = 0; i < 8; ++i)
      #pragma unroll
      for (int jj = 0; jj < 4; ++jj)
        #pragma unroll
        for (int r = 0; r < 4; ++r)
          C[(long)(m0 + cr + i * 16 + r) * 1024 + (n0 + cc + jj * 16)] = acc[i][jj][r];
  } else {
    unsigned short* C = (unsigned short*)C0;
    #pragma unroll
    for (int i = 0; i < 8; ++i)
      #pragma unroll
      for (int jj = 0; jj < 4; ++jj)
        #pragma unroll
        for (int r = 0; r < 4; ++r)
          C[(long)(m0 + cr + i * 16 + r) * 1024 + (n0 + cc + jj * 16)] = f2h(acc[i][jj][r]);
  }
}

// ---------- batched wrapper (QK^T, PV): fp32 C ----------
__global__ __launch_bounds__(512, 2)
void gemm_bt256(const unsigned short* __restrict__ A, const unsigned short* __restrict__ B,
                float* __restrict__ C, long aZ, long bZ, long cZ)
{
  __shared__ __align__(16) unsigned short lds[65536];   // 128 KiB
  // 256 blocks: bijective XCD-chunked swizzle (256 % 8 == 0) -> one batch per XCD
  const int bid = blockIdx.x;
  const int lin = (bid & 7) * 32 + (bid >> 3);
  const long z = lin >> 5;
  const int rr = lin & 31;
  gemm256_core<0>(A + z * aZ, B + z * bZ, (void*)(C + z * cZ),
                  (rr >> 2) * 256, (rr & 3) * 256, lds);
}

// ---------- merged projections: Qproj (256 blocks) + Kproj (128) + Vproj (128) ----------
__global__ __launch_bounds__(512, 2)
void proj_all256(const unsigned short* __restrict__ ch, const unsigned short* __restrict__ qh,
                 const unsigned short* __restrict__ wT,
                 unsigned short* __restrict__ Qf, unsigned short* __restrict__ Kf,
                 unsigned short* __restrict__ Vt)
{
  __shared__ __align__(16) unsigned short lds[65536];   // 128 KiB
  const int bid = blockIdx.x;
  const int lin = (bid & 7) * 64 + (bid >> 3);          // 512 % 8 == 0, bijective
  const long qBatch = 1024l * 1024;

  const unsigned short* pA;
  const unsigned short* pB;
  unsigned short* C;
  int m0, n0;
  if (lin < 256) {                  // Qproj: Q = c @ wq  [16384,1024]
    pA = ch; pB = wT; C = Qf;
    m0 = (lin >> 2) * 256; n0 = (lin & 3) * 256;
  } else if (lin < 384) {           // Kproj: K = q @ wk  [8192,1024]
    int i = lin - 256;
    pA = qh; pB = wT + (1l << 20); C = Kf;
    m0 = (i >> 2) * 256; n0 = (i & 3) * 256;
  } else {                          // Vproj: Vt[z][h,l] = wvT @ q[z]^T  [8][1024,1024]
    int i = lin - 384;
    long z = i >> 4;
    pA = wT + (2l << 20); pB = qh + z * qBatch; C = Vt + z * qBatch;
    m0 = ((i >> 2) & 3) * 256; n0 = (i & 3) * 256;
  }
  gemm256_core<1>(pA, pB, C, m0, n0, lds);
}

// ---------- merged prep: cvt_c (16384 blocks) + cvt_q (8192) + wtrans (3072) ----------
__global__ __launch_bounds__(256)
void prep_all(const float* __restrict__ q, const float* __restrict__ c,
              const float* __restrict__ wq, const float* __restrict__ wk,
              const float* __restrict__ wv,
              unsigned short* __restrict__ qh, unsigned short* __restrict__ ch,
              unsigned short* __restrict__ wT)
{
  __shared__ float tile[32][33];
  const int bid = blockIdx.x;
  const int t = threadIdx.x;

  if (bid < 24576) {                // fp32 -> fp16 convert, 1024 elems/block
    const float* x;
    unsigned short* y;
    long blk;
    if (bid < 16384) { x = c; y = ch; blk = bid; }
    else             { x = q; y = qh; blk = bid - 16384; }
    long i = (blk * 256 + t) * 4;
    float4 v = *(const float4*)(x + i);
    *(us4*)(y + i) = (us4){f2h(v.x), f2h(v.y), f2h(v.z), f2h(v.w)};
  } else {                          // weight transpose + convert
    int i = bid - 24576;
    const int d0 = (i & 31) * 32, h0 = ((i >> 5) & 31) * 32, id = i >> 10;
    const float* W = (id == 0) ? wq : ((id == 1) ? wk : wv);
    unsigned short* WT = wT + (long)id * (1 << 20);
    #pragma unroll
    for (int p = 0; p < 4; ++p) {
      int dl = p * 8 + (t >> 5), hl = t & 31;
      tile[dl][hl] = W[(long)(d0 + dl) * 1024 + h0 + hl];
    }
    __syncthreads();
    #pragma unroll
    for (int p = 0; p < 4; ++p) {
      int hr = p * 8 + (t >> 5), dc = t & 31;
      WT[(long)(h0 + hr) * 1024 + d0 + dc] = f2h(tile[dc][hr]);
    }
  }
}

// ---------- row softmax: 1 wave per row, 4 rows/block, no LDS/barriers ----------
__global__ __launch_bounds__(256)
void softmax_rows(const float* __restrict__ S, unsigned short* __restrict__ P)
{
  const long row = (long)blockIdx.x * 4 + (threadIdx.x >> 6);
  const int lane = threadIdx.x & 63;
  const float* Sr = S + row * 1024;

  float4 v[4];
  #pragma unroll
  for (int c = 0; c < 4; ++c) v[c] = *(const float4*)(Sr + c * 256 + lane * 4);

  float m = -1e30f;
  #pragma unroll
  for (int c = 0; c < 4; ++c)
    m = fmaxf(m, fmaxf(fmaxf(v[c].x, v[c].y), fmaxf(v[c].z, v[c].w)));
  #pragma unroll
  for (int off = 32; off > 0; off >>= 1) m = fmaxf(m, __shfl_xor(m, off));

  float e[4][4];
  float sum = 0.f;
  #pragma unroll
  for (int c = 0; c < 4; ++c) {
    e[c][0] = __expf(v[c].x - m); e[c][1] = __expf(v[c].y - m);
    e[c][2] = __expf(v[c].z - m); e[c][3] = __expf(v[c].w - m);
    sum += e[c][0] + e[c][1] + e[c][2] + e[c][3];
  }
  #pragma unroll
  for (int off = 32; off > 0; off >>= 1) sum += __shfl_xor(sum, off);

  const float inv = 1.0f / sum;
  unsigned short* Pr = P + row * 1024;
  #pragma unroll
  for (int c = 0; c < 4; ++c) {
    us4 o = {f2h(e[c][0] * inv), f2h(e[c][1] * inv),
             f2h(e[c][2] * inv), f2h(e[c][3] * inv)};
    *(us4*)(Pr + c * 256 + lane * 4) = o;
  }
}

// ---------- host ----------
extern "C" void kernel_launch(void* const* d_in, const int* in_sizes, int n_in,
                              void* d_out, int out_size, void* d_ws, size_t ws_size,
                              hipStream_t stream)
{
  (void)in_sizes; (void)n_in; (void)out_size; (void)ws_size;
  // inputs: q [8,1024,1024], c [8,2048,1024], wq, wk, wv [1024,1024], all fp32
  const float* q  = (const float*)d_in[0];
  const float* c  = (const float*)d_in[1];
  const float* wq = (const float*)d_in[2];
  const float* wk = (const float*)d_in[3];
  const float* wv = (const float*)d_in[4];
  float* out = (float*)d_out;   // [8, 2048, 1024]; also S scratch

  const size_t MB = 1ull << 20;
  const long cBatch = 2048l * 1024;   // c/Q/S/out elems per batch
  const long qBatch = 1024l * 1024;   // q/K/V elems per batch

  char* ws = (char*)d_ws;
  size_t off = 0;
  auto take = [&](size_t bytes) -> unsigned short* {
    unsigned short* p = (unsigned short*)(ws + off);
    off += bytes;
    return p;
  };
  // 118 MB total
  unsigned short* wT = take(6 * MB);    // 3x [1024(h),1024(d)] fp16: wqT, wkT, wvT
  unsigned short* qh = take(16 * MB);   // [8192,1024] fp16
  unsigned short* ch = take(32 * MB);   // [16384,1024] fp16; P aliases after Qproj
  unsigned short* Kf = take(16 * MB);   // [8192,1024] fp16
  unsigned short* Vt = take(16 * MB);   // [8][1024(h),1024(lq)] fp16
  unsigned short* Qf = take(32 * MB);   // [16384,1024] fp16
  unsigned short* Pf = ch;              // [16384,1024] fp16 (c-f16 dead after Qproj)

  // 1) prep: c->fp16, q->fp16, weights transpose->fp16
  prep_all<<<27648, 256, 0, stream>>>(q, c, wq, wk, wv, qh, ch, wT);
  // 2) all three projections, cross-phase-pipelined 256^2 core (512 blocks)
  proj_all256<<<512, 512, 0, stream>>>(ch, qh, wT, Qf, Kf, Vt);
  // 3) QK^T: S[c,qt] = sum_h Q[c,h] * K[qt,h]  (S fp32 in d_out region)
  gemm_bt256<<<256, 512, 0, stream>>>(Qf, Kf, out, cBatch, qBatch, cBatch);
  // 4) softmax rows -> P fp16 (1 wave/row, 4 rows/block)
  softmax_rows<<<4096, 256, 0, stream>>>(out, Pf);
  // 5) PV: out[c,h] = sum_qt P[c,qt] * Vt[h,qt]
  gemm_bt256<<<256, 512, 0, stream>>>(Pf, Vt, out, cBatch, qBatch, cBatch);
}

// Round 10
// 308.195 us; speedup vs baseline: 1.0222x; 1.0222x over previous
//
#include <hip/hip_runtime.h>
#include <stdint.h>

// ---------- types ----------
typedef _Float16 half8 __attribute__((ext_vector_type(8)));   // 8 fp16 (4 VGPRs) MFMA frag
typedef __attribute__((ext_vector_type(4))) float f32x4;      // MFMA acc
typedef __attribute__((ext_vector_type(4))) unsigned short us4;

__device__ __forceinline__ unsigned short f2h(float f) {
  _Float16 h = (_Float16)f;              // v_cvt_f16_f32, RTE
  return __builtin_bit_cast(unsigned short, h);
}

// async global->LDS, 16B per lane (dst = wave-uniform base + lane*16)
__device__ __forceinline__ void async_cp16(const unsigned short* g, unsigned short* l) {
  __builtin_amdgcn_global_load_lds(
      (const __attribute__((address_space(1))) void*)g,
      (__attribute__((address_space(3))) void*)l, 16, 0, 0);
}

// =====================================================================
// Round-10: RESUBMIT of round 9 (infra failure, no data). R7 banked best
// + T5 setprio ONLY — single-variable A/B. setprio cannot hang (R8 ran
// the identical macros to completion); round-9's "container failed
// twice" is attributed to infrastructure.
//
// R2/R7 GEMM core: 256x256 tile, C = A[M,1024] * B[N,1024]^T, fp16 in /
// fp32 acc, 512 threads = 8 waves (2M x 4N), per-wave 128x64, 16x16x32.
// One barrier per phase; compiler-scheduled regions; counted vmcnt(4)
// once per K-tile. 0 bank conflicts (measured).
// Pre-committed readout: proj 58-64us => T5 confirmed; proj 70-74us =>
// T5 null (lockstep-null per m190) and the 7-variant plateau stands.
// =====================================================================

#define BARF() { asm volatile("" ::: "memory"); \
                 __builtin_amdgcn_s_barrier(); \
                 asm volatile("" ::: "memory"); }

#define MFMA_QUAD(IOFF) \
  __builtin_amdgcn_s_setprio(1); \
  _Pragma("unroll") \
  for (int ii = 0; ii < 4; ++ii) { \
    _Pragma("unroll") \
    for (int jj = 0; jj < 4; ++jj) \
      acc[(IOFF) + ii][jj] = __builtin_amdgcn_mfma_f32_16x16x32_f16( \
          a[ii], b[jj], acc[(IOFF) + ii][jj], 0, 0, 0); \
  } \
  __builtin_amdgcn_s_setprio(0);

// One K-tile (4 single-barrier phases). BUF = J&1 (literal). J = runtime.
// WAITN: 4 = steady-state counted wait, 0 = tail drain, -1 = none.
#define KTILE(BUF, J, ST1, ST2, WAITN) { \
  /* ---- P1: quad (m-half 0, k-half 0) + stage (J+1) A-kh1 ---- */ \
  BARF(); \
  { \
    _Pragma("unroll") \
    for (int jj = 0; jj < 4; ++jj) b[jj] = *(const half8*)&lds[(BUF)*32768 + 16384 + offB[jj]]; \
    _Pragma("unroll") \
    for (int ii = 0; ii < 4; ++ii) a[ii] = *(const half8*)&lds[(BUF)*32768 + offA[ii]]; \
    if (ST1) { const unsigned short* s_ = sA + (J + 1) * 64 + 32; \
      async_cp16(s_ + g0, lds + (1 - (BUF)) * 32768 + 8192 + d0); \
      async_cp16(s_ + g1, lds + (1 - (BUF)) * 32768 + 8192 + d1); } \
    MFMA_QUAD(0) \
  } \
  /* ---- P2: quad (m-half 1, k-half 0); B frags reused; stage (J+1) B-kh1 ---- */ \
  BARF(); \
  { \
    _Pragma("unroll") \
    for (int ii = 0; ii < 4; ++ii) a[ii] = *(const half8*)&lds[(BUF)*32768 + offA[4 + ii]]; \
    if (ST1) { const unsigned short* s_ = sB + (J + 1) * 64 + 32; \
      async_cp16(s_ + g0, lds + (1 - (BUF)) * 32768 + 24576 + d0); \
      async_cp16(s_ + g1, lds + (1 - (BUF)) * 32768 + 24576 + d1); } \
    MFMA_QUAD(4) \
  } \
  /* ---- P3: quad (m-half 0, k-half 1); kh0 dead -> stage (J+2) A-kh0 here ---- */ \
  BARF(); \
  { \
    _Pragma("unroll") \
    for (int jj = 0; jj < 4; ++jj) b[jj] = *(const half8*)&lds[(BUF)*32768 + 24576 + offB[jj]]; \
    _Pragma("unroll") \
    for (int ii = 0; ii < 4; ++ii) a[ii] = *(const half8*)&lds[(BUF)*32768 + 8192 + offA[ii]]; \
    if (ST2) { const unsigned short* s_ = sA + (J + 2) * 64; \
      async_cp16(s_ + g0, lds + (BUF) * 32768 + d0); \
      async_cp16(s_ + g1, lds + (BUF) * 32768 + d1); } \
    MFMA_QUAD(0) \
  } \
  /* ---- P4: quad (m-half 1, k-half 1); stage (J+2) B-kh0; boundary vmcnt ---- */ \
  BARF(); \
  { \
    _Pragma("unroll") \
    for (int ii = 0; ii < 4; ++ii) a[ii] = *(const half8*)&lds[(BUF)*32768 + 8192 + offA[4 + ii]]; \
    if (ST2) { const unsigned short* s_ = sB + (J + 2) * 64; \
      async_cp16(s_ + g0, lds + (BUF) * 32768 + 16384 + d0); \
      async_cp16(s_ + g1, lds + (BUF) * 32768 + 16384 + d1); } \
    MFMA_QUAD(4) \
  } \
  if ((WAITN) == 4)      asm volatile("s_waitcnt vmcnt(4)" ::: "memory"); \
  else if ((WAITN) == 0) asm volatile("s_waitcnt vmcnt(0)" ::: "memory"); \
}

template<int EPI>   // 0 = fp32 C, 1 = fp16 C
__device__ __forceinline__ void gemm256_core(
    const unsigned short* __restrict__ pA, const unsigned short* __restrict__ pB,
    void* __restrict__ C0, int m0, int n0, unsigned short* lds)
{
  const int t = threadIdx.x;

  // ---- staging per-thread constants (pid -> (row, slot) -> logical kq) ----
  const int r0 = t >> 2;
  const int kq0 = ((t & 3) - (r0 >> 1)) & 3;
  const int r1 = (512 + t) >> 2;
  const int kq1 = ((t & 3) - (r1 >> 1)) & 3;
  const long g0 = (long)r0 * 1024 + kq0 * 8;   // global elem offset (row-major, K=1024)
  const long g1 = (long)r1 * 1024 + kq1 * 8;
  const int d0 = t * 8;                        // LDS elem offset of chunk pid0 (=t)
  const int d1 = (512 + t) * 8;                // chunk pid1 (=512+t)

  const unsigned short* sA = pA + (long)m0 * 1024;
  const unsigned short* sB = pB + (long)n0 * 1024;

  // ---- MFMA fragment geometry ----
  const int w  = t >> 6;
  const int l  = t & 63;
  const int wm = (w >> 2) * 128;     // 2 m-waves
  const int wn = (w & 3) * 64;       // 4 n-waves
  const int lm = l & 15;
  const int kq = l >> 4;

  // loop-invariant swizzled LDS read offsets (elements, region-relative)
  int offA[8], offB[4];
  #pragma unroll
  for (int i = 0; i < 8; ++i) {
    int r = wm + i * 16 + lm;
    offA[i] = r * 32 + (((kq + (r >> 1)) & 3) * 8);
  }
  #pragma unroll
  for (int j = 0; j < 4; ++j) {
    int r = wn + j * 16 + lm;
    offB[j] = r * 32 + (((kq + (r >> 1)) & 3) * 8);
  }

  f32x4 acc[8][4];
  #pragma unroll
  for (int i = 0; i < 8; ++i)
    #pragma unroll
    for (int j = 0; j < 4; ++j)
      acc[i][j] = (f32x4){0.f, 0.f, 0.f, 0.f};

  half8 a[4], b[4];

  // ---- prologue: stage buf0 {A,B}x{kh0,kh1} + buf1 {A,B} kh0 (12 loads) ----
  async_cp16(sA + g0,      lds + 0     + d0);  async_cp16(sA + g1,      lds + 0     + d1);
  async_cp16(sB + g0,      lds + 16384 + d0);  async_cp16(sB + g1,      lds + 16384 + d1);
  async_cp16(sA + g0 + 32, lds + 8192  + d0);  async_cp16(sA + g1 + 32, lds + 8192  + d1);
  async_cp16(sB + g0 + 32, lds + 24576 + d0);  async_cp16(sB + g1 + 32, lds + 24576 + d1);
  async_cp16(sA + g0 + 64, lds + 32768 + d0);  async_cp16(sA + g1 + 64, lds + 32768 + d1);
  async_cp16(sB + g0 + 64, lds + 49152 + d0);  async_cp16(sB + g1 + 64, lds + 49152 + d1);
  asm volatile("s_waitcnt vmcnt(4)" ::: "memory");   // buf0 fully landed; buf1-kh0 in flight
  // (first KTILE's P1 barrier completes the cross-wave handoff)

  // ---- main loop: K = 1024 -> 16 K-tiles ----
  for (int j2 = 0; j2 < 7; ++j2) {
    const int j = j2 * 2;
    KTILE(0, j,     1, 1, 4)
    KTILE(1, j + 1, 1, 1, 4)
  }
  KTILE(0, 14, 1, 0, 0)    // stages tile 15 kh1; drains everything
  KTILE(1, 15, 0, 0, -1)   // pure compute tail

  // ---- epilogue. C/D layout (m89-verified): col = lane&15, row = (lane>>4)*4 + reg ----
  const int cr = wm + (l >> 4) * 4;
  const int cc = wn + lm;
  if (EPI == 0) {
    float* C = (float*)C0;
    #pragma unroll
    for (int i = 0; i < 8; ++i)
      #pragma unroll
      for (int jj = 0; jj < 4; ++jj)
        #pragma unroll
        for (int r = 0; r < 4; ++r)
          C[(long)(m0 + cr + i * 16 + r) * 1024 + (n0 + cc + jj * 16)] = acc[i][jj][r];
  } else {
    unsigned short* C = (unsigned short*)C0;
    #pragma unroll
    for (int i = 0; i < 8; ++i)
      #pragma unroll
      for (int jj = 0; jj < 4; ++jj)
        #pragma unroll
        for (int r = 0; r < 4; ++r)
          C[(long)(m0 + cr + i * 16 + r) * 1024 + (n0 + cc + jj * 16)] = f2h(acc[i][jj][r]);
  }
}

// ---------- batched wrapper (QK^T, PV): fp32 C ----------
__global__ __launch_bounds__(512, 2)
void gemm_bt256(const unsigned short* __restrict__ A, const unsigned short* __restrict__ B,
                float* __restrict__ C, long aZ, long bZ, long cZ)
{
  __shared__ __align__(16) unsigned short lds[65536];   // 128 KiB
  // 256 blocks: bijective XCD-chunked swizzle (256 % 8 == 0) -> one batch per XCD
  const int bid = blockIdx.x;
  const int lin = (bid & 7) * 32 + (bid >> 3);
  const long z = lin >> 5;
  const int rr = lin & 31;
  gemm256_core<0>(A + z * aZ, B + z * bZ, (void*)(C + z * cZ),
                  (rr >> 2) * 256, (rr & 3) * 256, lds);
}

// ---------- merged projections: Qproj (256 blocks) + Kproj (128) + Vproj (128) ----------
__global__ __launch_bounds__(512, 2)
void proj_all256(const unsigned short* __restrict__ ch, const unsigned short* __restrict__ qh,
                 const unsigned short* __restrict__ wT,
                 unsigned short* __restrict__ Qf, unsigned short* __restrict__ Kf,
                 unsigned short* __restrict__ Vt)
{
  __shared__ __align__(16) unsigned short lds[65536];   // 128 KiB
  const int bid = blockIdx.x;
  const int lin = (bid & 7) * 64 + (bid >> 3);          // 512 % 8 == 0, bijective
  const long qBatch = 1024l * 1024;

  const unsigned short* pA;
  const unsigned short* pB;
  unsigned short* C;
  int m0, n0;
  if (lin < 256) {                  // Qproj: Q = c @ wq  [16384,1024]
    pA = ch; pB = wT; C = Qf;
    m0 = (lin >> 2) * 256; n0 = (lin & 3) * 256;
  } else if (lin < 384) {           // Kproj: K = q @ wk  [8192,1024]
    int i = lin - 256;
    pA = qh; pB = wT + (1l << 20); C = Kf;
    m0 = (i >> 2) * 256; n0 = (i & 3) * 256;
  } else {                          // Vproj: Vt[z][h,l] = wvT @ q[z]^T  [8][1024,1024]
    int i = lin - 384;
    long z = i >> 4;
    pA = wT + (2l << 20); pB = qh + z * qBatch; C = Vt + z * qBatch;
    m0 = ((i >> 2) & 3) * 256; n0 = (i & 3) * 256;
  }
  gemm256_core<1>(pA, pB, C, m0, n0, lds);
}

// ---------- merged prep: cvt_c (16384 blocks) + cvt_q (8192) + wtrans (3072) ----------
__global__ __launch_bounds__(256)
void prep_all(const float* __restrict__ q, const float* __restrict__ c,
              const float* __restrict__ wq, const float* __restrict__ wk,
              const float* __restrict__ wv,
              unsigned short* __restrict__ qh, unsigned short* __restrict__ ch,
              unsigned short* __restrict__ wT)
{
  __shared__ float tile[32][33];
  const int bid = blockIdx.x;
  const int t = threadIdx.x;

  if (bid < 24576) {                // fp32 -> fp16 convert, 1024 elems/block
    const float* x;
    unsigned short* y;
    long blk;
    if (bid < 16384) { x = c; y = ch; blk = bid; }
    else             { x = q; y = qh; blk = bid - 16384; }
    long i = (blk * 256 + t) * 4;
    float4 v = *(const float4*)(x + i);
    *(us4*)(y + i) = (us4){f2h(v.x), f2h(v.y), f2h(v.z), f2h(v.w)};
  } else {                          // weight transpose + convert
    int i = bid - 24576;
    const int d0 = (i & 31) * 32, h0 = ((i >> 5) & 31) * 32, id = i >> 10;
    const float* W = (id == 0) ? wq : ((id == 1) ? wk : wv);
    unsigned short* WT = wT + (long)id * (1 << 20);
    #pragma unroll
    for (int p = 0; p < 4; ++p) {
      int dl = p * 8 + (t >> 5), hl = t & 31;
      tile[dl][hl] = W[(long)(d0 + dl) * 1024 + h0 + hl];
    }
    __syncthreads();
    #pragma unroll
    for (int p = 0; p < 4; ++p) {
      int hr = p * 8 + (t >> 5), dc = t & 31;
      WT[(long)(h0 + hr) * 1024 + d0 + dc] = f2h(tile[dc][hr]);
    }
  }
}

// ---------- row softmax: 1 wave per row, 4 rows/block, no LDS/barriers ----------
__global__ __launch_bounds__(256)
void softmax_rows(const float* __restrict__ S, unsigned short* __restrict__ P)
{
  const long row = (long)blockIdx.x * 4 + (threadIdx.x >> 6);
  const int lane = threadIdx.x & 63;
  const float* Sr = S + row * 1024;

  float4 v[4];
  #pragma unroll
  for (int c = 0; c < 4; ++c) v[c] = *(const float4*)(Sr + c * 256 + lane * 4);

  float m = -1e30f;
  #pragma unroll
  for (int c = 0; c < 4; ++c)
    m = fmaxf(m, fmaxf(fmaxf(v[c].x, v[c].y), fmaxf(v[c].z, v[c].w)));
  #pragma unroll
  for (int off = 32; off > 0; off >>= 1) m = fmaxf(m, __shfl_xor(m, off));

  float e[4][4];
  float sum = 0.f;
  #pragma unroll
  for (int c = 0; c < 4; ++c) {
    e[c][0] = __expf(v[c].x - m); e[c][1] = __expf(v[c].y - m);
    e[c][2] = __expf(v[c].z - m); e[c][3] = __expf(v[c].w - m);
    sum += e[c][0] + e[c][1] + e[c][2] + e[c][3];
  }
  #pragma unroll
  for (int off = 32; off > 0; off >>= 1) sum += __shfl_xor(sum, off);

  const float inv = 1.0f / sum;
  unsigned short* Pr = P + row * 1024;
  #pragma unroll
  for (int c = 0; c < 4; ++c) {
    us4 o = {f2h(e[c][0] * inv), f2h(e[c][1] * inv),
             f2h(e[c][2] * inv), f2h(e[c][3] * inv)};
    *(us4*)(Pr + c * 256 + lane * 4) = o;
  }
}

// ---------- host ----------
extern "C" void kernel_launch(void* const* d_in, const int* in_sizes, int n_in,
                              void* d_out, int out_size, void* d_ws, size_t ws_size,
                              hipStream_t stream)
{
  (void)in_sizes; (void)n_in; (void)out_size; (void)ws_size;
  // inputs: q [8,1024,1024], c [8,2048,1024], wq, wk, wv [1024,1024], all fp32
  const float* q  = (const float*)d_in[0];
  const float* c  = (const float*)d_in[1];
  const float* wq = (const float*)d_in[2];
  const float* wk = (const float*)d_in[3];
  const float* wv = (const float*)d_in[4];
  float* out = (float*)d_out;   // [8, 2048, 1024]; also S scratch

  const size_t MB = 1ull << 20;
  const long cBatch = 2048l * 1024;   // c/Q/S/out elems per batch
  const long qBatch = 1024l * 1024;   // q/K/V elems per batch

  char* ws = (char*)d_ws;
  size_t off = 0;
  auto take = [&](size_t bytes) -> unsigned short* {
    unsigned short* p = (unsigned short*)(ws + off);
    off += bytes;
    return p;
  };
  // 118 MB total
  unsigned short* wT = take(6 * MB);    // 3x [1024(h),1024(d)] fp16: wqT, wkT, wvT
  unsigned short* qh = take(16 * MB);   // [8192,1024] fp16
  unsigned short* ch = take(32 * MB);   // [16384,1024] fp16; P aliases after Qproj
  unsigned short* Kf = take(16 * MB);   // [8192,1024] fp16
  unsigned short* Vt = take(16 * MB);   // [8][1024(h),1024(lq)] fp16
  unsigned short* Qf = take(32 * MB);   // [16384,1024] fp16
  unsigned short* Pf = ch;              // [16384,1024] fp16 (c-f16 dead after Qproj)

  // 1) prep: c->fp16, q->fp16, weights transpose->fp16
  prep_all<<<27648, 256, 0, stream>>>(q, c, wq, wk, wv, qh, ch, wT);
  // 2) all three projections, R2 core + setprio (512 blocks, 2 rounds)
  proj_all256<<<512, 512, 0, stream>>>(ch, qh, wT, Qf, Kf, Vt);
  // 3) QK^T: S[c,qt] = sum_h Q[c,h] * K[qt,h]  (S fp32 in d_out region)
  gemm_bt256<<<256, 512, 0, stream>>>(Qf, Kf, out, cBatch, qBatch, cBatch);
  // 4) softmax rows -> P fp16 (1 wave/row, 4 rows/block)
  softmax_rows<<<4096, 256, 0, stream>>>(out, Pf);
  // 5) PV: out[c,h] = sum_qt P[c,qt] * Vt[h,qt]
  gemm_bt256<<<256, 512, 0, stream>>>(Pf, Vt, out, cBatch, qBatch, cBatch);
}